// Round 5
// baseline (330.265 us; speedup 1.0000x reference)
//
#include <hip/hip_runtime.h>
#include <hip/hip_bf16.h>
#include <cmath>

#define TSEQ 2048
#define DMODEL 1024
#define NHEAD 16
#define HDIM 64
#define BATCH 4
#define MTOT (BATCH*TSEQ)   // 8192

typedef __attribute__((ext_vector_type(8))) short bf16x8;
typedef __attribute__((ext_vector_type(4))) float f32x4;
typedef __attribute__((ext_vector_type(16))) float f32x16;
typedef unsigned short u16;
typedef unsigned int u32;
typedef __attribute__((ext_vector_type(2))) unsigned int u32x2;

#define QSCALE 0.18033688011112042f   // 0.125 * log2(e)

__device__ __forceinline__ u16 f2bf(float f) {
    union { float f; unsigned u; } v; v.f = f;
    unsigned r = (v.u + 0x7fffu + ((v.u >> 16) & 1u)) >> 16;
    return (u16)r;
}

__device__ __forceinline__ u32 cvtpk(float a, float b) {
    u32 r;
    asm("v_cvt_pk_bf16_f32 %0, %1, %2" : "=v"(r) : "v"(a), "v"(b));
    return r;
}

// cross-half exchange: returns {v0,v1} with v0 op v1 == x op partner(x) on every lane
__device__ __forceinline__ float2 swap32(float x) {
    union { float f; u32 u; } a; a.f = x;
    u32x2 r = __builtin_amdgcn_permlane32_swap(a.u, a.u, 0, 0);
    union { u32 u; float f; } p, q;
    p.u = r[0]; q.u = r[1];
    return make_float2(p.f, q.f);
}

// async global->LDS, 16B per lane; LDS dest is wave-uniform base (+lane*16 by HW)
#define GLOAD16(g, s) __builtin_amdgcn_global_load_lds( \
    (const __attribute__((address_space(1))) void*)(g), \
    (__attribute__((address_space(3))) void*)(s), 16, 0, 0)

// ---------------- converters ----------------
__global__ __launch_bounds__(256) void cvt_x(const float* __restrict__ x,
                                             u16* __restrict__ xb) {
    int i = (blockIdx.x * 256 + threadIdx.x) * 4;
    float4 v = *(const float4*)(x + i);
    ushort4 o;
    o.x = f2bf(v.x); o.y = f2bf(v.y); o.z = f2bf(v.z); o.w = f2bf(v.w);
    *(ushort4*)(xb + i) = o;
}

// WT[n][k] = bf16(W[k][n]); 64x64 tiles
__global__ __launch_bounds__(256) void wtrans(const float* __restrict__ W,
                                              u16* __restrict__ WT) {
    __shared__ float tile[64][65];
    int n0 = blockIdx.x * 64, k0 = blockIdx.y * 64;
    int t = threadIdx.x;
    int r = t >> 4;
    int c4 = (t & 15) * 4;
#pragma unroll
    for (int rr = 0; rr < 4; rr++) {
        int k = rr * 16 + r;
        float4 v = *(const float4*)(W + (size_t)(k0 + k) * DMODEL + n0 + c4);
        tile[k][c4 + 0] = v.x; tile[k][c4 + 1] = v.y;
        tile[k][c4 + 2] = v.z; tile[k][c4 + 3] = v.w;
    }
    __syncthreads();
#pragma unroll
    for (int rr = 0; rr < 4; rr++) {
        int n = rr * 16 + r;
        ushort4 o;
        o.x = f2bf(tile[c4 + 0][n]);
        o.y = f2bf(tile[c4 + 1][n]);
        o.z = f2bf(tile[c4 + 2][n]);
        o.w = f2bf(tile[c4 + 3][n]);
        *(ushort4*)(WT + (size_t)(n0 + n) * DMODEL + k0 + c4) = o;
    }
}

__global__ __launch_bounds__(256) void pack_bias(const float* __restrict__ bq,
                                                 const float* __restrict__ bk,
                                                 const float* __restrict__ bv,
                                                 float* __restrict__ bp) {
    int i = blockIdx.x * 256 + threadIdx.x;   // 0..3071
    float v = (i < 1024) ? bq[i] * QSCALE : (i < 2048) ? bk[i - 1024] : bv[i - 2048];
    bp[i] = v;
}

// ---------------- GEMM: 128x128 tile, BK=32, 3-buffer counted-vmcnt pipeline ----------------
// MODE 0: fused QKV (N=3072): seg0->Qg (pre-scaled by QSCALE), seg1->Kg, seg2->VTg
// MODE 3: f32 out [M][N]
template<int MODE>
__global__ __launch_bounds__(256) void gemm_bt(const u16* __restrict__ A,
                                               const u16* __restrict__ BT,
                                               const float* __restrict__ bias,
                                               u16* __restrict__ Qg,
                                               u16* __restrict__ Kg,
                                               u16* __restrict__ VTg,
                                               float* __restrict__ Fout,
                                               int K) {
    __shared__ __align__(16) u16 lds[6 * 4096];   // lA bufs 0..2, lB bufs 0..2 (48 KB)
    // XCD-chunked swizzle (nwg multiple of 8)
    int nwg = gridDim.x * gridDim.y;
    int bid = blockIdx.y * gridDim.x + blockIdx.x;
    int cpx = nwg >> 3;
    int swz = (bid & 7) * cpx + (bid >> 3);
    int bx = swz % gridDim.x, by = swz / gridDim.x;
    int m0 = by * 128, n0 = bx * 128;
    int t = threadIdx.x, l = t & 63, w = t >> 6;
    int wr = w >> 1, wc = w & 1;
    int lg = l >> 4, lr = l & 15;
    f32x4 acc[4][4];
#pragma unroll
    for (int i = 0; i < 4; i++)
#pragma unroll
        for (int j = 0; j < 4; j++) acc[i][j] = (f32x4){0.f, 0.f, 0.f, 0.f};

    auto STAGE = [&](int kt, int nbuf) {
        int k0 = kt << 5;
#pragma unroll
        for (int s = 0; s < 2; ++s) {
            int cc = t + s * 256;
            int row = cc >> 2, ko = (cc & 3) * 8;
            GLOAD16(A  + (size_t)(m0 + row) * K + k0 + ko,
                    lds + nbuf * 4096 + (s * 256 + w * 64) * 8);
            GLOAD16(BT + (size_t)(n0 + row) * K + k0 + ko,
                    lds + 12288 + nbuf * 4096 + (s * 256 + w * 64) * 8);
        }
    };

    const int KT = K >> 5;
    STAGE(0, 0);
    STAGE(1, 1);
    asm volatile("s_waitcnt vmcnt(4)" ::: "memory");
    __syncthreads();
    int cur = 0;
    for (int kt = 0; kt < KT; ++kt) {
        int sb = cur + 2; if (sb >= 3) sb -= 3;
        if (kt + 2 < KT) STAGE(kt + 2, sb);
        const u16* a_ = lds + cur * 4096;
        const u16* b_ = lds + 12288 + cur * 4096;
        bf16x8 af[4], bfr[4];
#pragma unroll
        for (int i = 0; i < 4; i++) {
            af[i]  = *(const bf16x8*)(a_ + (wr * 64 + i * 16 + lr) * 32 + lg * 8);
            bfr[i] = *(const bf16x8*)(b_ + (wc * 64 + i * 16 + lr) * 32 + lg * 8);
        }
        __builtin_amdgcn_s_setprio(1);
#pragma unroll
        for (int mi = 0; mi < 4; mi++)
#pragma unroll
            for (int ni = 0; ni < 4; ni++)
                acc[mi][ni] = __builtin_amdgcn_mfma_f32_16x16x32_bf16(
                    af[mi], bfr[ni], acc[mi][ni], 0, 0, 0);
        __builtin_amdgcn_s_setprio(0);
        if (kt + 2 < KT)      asm volatile("s_waitcnt vmcnt(4)" ::: "memory");
        else if (kt + 1 < KT) asm volatile("s_waitcnt vmcnt(0)" ::: "memory");
        __syncthreads();
        cur = (cur == 2) ? 0 : cur + 1;
    }

    if (MODE == 0) {
        int seg = n0 >> 10;                       // block-uniform
        float ss = (seg == 0) ? QSCALE : 1.0f;
        u16* outb = (seg == 0) ? Qg : (seg == 1) ? Kg : VTg;
#pragma unroll
        for (int mi = 0; mi < 4; mi++)
#pragma unroll
            for (int ni = 0; ni < 4; ni++) {
                int ng = n0 + wc * 64 + ni * 16 + lr;
                int ngl = ng & 1023;
                int h = ngl >> 6, d = ngl & 63;
                int mg0 = m0 + wr * 64 + mi * 16 + lg * 4;
                int bb = mg0 >> 11, tq0 = mg0 & 2047;
                float bsv = bias[ng];
                if (seg == 2) {
                    ushort4 o;
                    o.x = f2bf(acc[mi][ni][0] + bsv);
                    o.y = f2bf(acc[mi][ni][1] + bsv);
                    o.z = f2bf(acc[mi][ni][2] + bsv);
                    o.w = f2bf(acc[mi][ni][3] + bsv);
                    *(ushort4*)&VTg[(((size_t)(bb * NHEAD + h)) * HDIM + d) * TSEQ + tq0] = o;
                } else {
#pragma unroll
                    for (int r = 0; r < 4; r++) {
                        float v = acc[mi][ni][r] * ss + bsv;
                        outb[(((size_t)(bb * NHEAD + h)) * TSEQ + tq0 + r) * HDIM + d] = f2bf(v);
                    }
                }
            }
    } else {
#pragma unroll
        for (int mi = 0; mi < 4; mi++)
#pragma unroll
            for (int ni = 0; ni < 4; ni++) {
                int ng = n0 + wc * 64 + ni * 16 + lr;
                int mg0 = m0 + wr * 64 + mi * 16 + lg * 4;
                float bsv = bias[ng];
#pragma unroll
                for (int r = 0; r < 4; r++)
                    Fout[(size_t)(mg0 + r) * DMODEL + ng] = acc[mi][ni][r] + bsv;
            }
    }
}

// ---------------- flash attention: 32x32 swapped, in-register softmax ----------------
// Q: [bh][T][64] bf16 pre-scaled by QSCALE; K: [bh][T][64]; VT: [bh][64][T]; O: [M][D] bf16
// block = 4 waves, 32 q/wave = 128 q-rows per pass; 2 passes (q-super p and 15-p)
__global__ __launch_bounds__(256) void attn(const u16* __restrict__ Qg,
                                            const u16* __restrict__ Kg,
                                            const u16* __restrict__ VTg,
                                            u16* __restrict__ Og) {
    __shared__ __align__(16) u16 sK[3 * 4096];
    __shared__ __align__(16) u16 sV[3 * 4096];
    const int bh = blockIdx.x;       // 0..63  (stride-64 ids -> same XCD per bh)
    const int p  = blockIdx.y;       // 0..7
    const int tid = threadIdx.x;
    const int wv = tid >> 6;
    const int l  = tid & 63;
    const int ln = l & 31;
    const int hi = l >> 5;
    const int b = bh >> 4, h = bh & 15;

    auto STAGE = [&](int tt, int nbuf) {
        int kv0s = tt << 6;
#pragma unroll
        for (int s = 0; s < 2; ++s) {
            int cc = tid + s * 256;
            int row = cc >> 3, c = cc & 7;
            int csrc = c ^ (row & 7);
            GLOAD16(Kg + ((size_t)bh * TSEQ + kv0s + row) * HDIM + csrc * 8,
                    sK + nbuf * 4096 + (s * 256 + wv * 64) * 8);
            GLOAD16(VTg + ((size_t)bh * HDIM + row) * TSEQ + kv0s + csrc * 8,
                    sV + nbuf * 4096 + (s * 256 + wv * 64) * 8);
        }
    };

    for (int pass = 0; pass < 2; ++pass) {
        const int sidx = pass ? (15 - p) : p;
        const int qs = sidx << 7;
        const int NT = (qs >> 6) + 2;            // >= 2
        const int q0w = qs + wv * 32;
        const int qglob = q0w + ln;

        bf16x8 qf0, qf1, qf2, qf3;
        {
            const u16* qb = Qg + ((size_t)bh * TSEQ + qglob) * HDIM + hi * 8;
            qf0 = *(const bf16x8*)(qb);
            qf1 = *(const bf16x8*)(qb + 16);
            qf2 = *(const bf16x8*)(qb + 32);
            qf3 = *(const bf16x8*)(qb + 48);
        }
        float mrun = -INFINITY, lsum = 0.f;
        f32x16 accO0, accO1;
#pragma unroll
        for (int i = 0; i < 16; ++i) { accO0[i] = 0.f; accO1[i] = 0.f; }

        STAGE(0, 0);
        STAGE(1, 1);
        asm volatile("s_waitcnt vmcnt(4)" ::: "memory");
        __syncthreads();
        int cur = 0;

        for (int t = 0; t < NT; ++t) {
            int sb = cur + 2; if (sb >= 3) sb -= 3;
            if (t + 2 < NT) STAGE(t + 2, sb);
            const int kv0 = t << 6;
            if (kv0 <= q0w + 31) {          // wave-uniform active check
                const u16* sKb = sK + cur * 4096;
                const u16* sVb = sV + cur * 4096;
                f32x16 sc0, sc1;
#pragma unroll
                for (int i = 0; i < 16; ++i) { sc0[i] = 0.f; sc1[i] = 0.f; }
                __builtin_amdgcn_s_setprio(1);
#pragma unroll
                for (int c = 0; c < 4; ++c) {
                    int u = ((c << 1) | hi) ^ (ln & 7);
                    bf16x8 kf0 = *(const bf16x8*)(sKb + ln * 64 + u * 8);
                    bf16x8 kf1 = *(const bf16x8*)(sKb + (32 + ln) * 64 + u * 8);
                    bf16x8 qq = (c == 0) ? qf0 : (c == 1) ? qf1 : (c == 2) ? qf2 : qf3;
                    sc0 = __builtin_amdgcn_mfma_f32_32x32x16_bf16(kf0, qq, sc0, 0, 0, 0);
                    sc1 = __builtin_amdgcn_mfma_f32_32x32x16_bf16(kf1, qq, sc1, 0, 0, 0);
                }
                __builtin_amdgcn_s_setprio(0);

                if (kv0 + 63 > q0w) {       // diagonal tile: apply causal mask
                    const int qrel = qglob - kv0;
#pragma unroll
                    for (int r = 0; r < 16; ++r) {
                        int e0 = (r & 3) + 8 * (r >> 2) + 4 * hi;
                        if (e0 > qrel) sc0[r] = -INFINITY;
                        if (e0 + 32 > qrel) sc1[r] = -INFINITY;
                    }
                }

                // tree max over the lane's 32 values, then cross-half via permlane
                float mx[8];
#pragma unroll
                for (int r = 0; r < 8; ++r)
                    mx[r] = fmaxf(fmaxf(sc0[r], sc0[r + 8]), fmaxf(sc1[r], sc1[r + 8]));
                mx[0] = fmaxf(mx[0], mx[4]); mx[1] = fmaxf(mx[1], mx[5]);
                mx[2] = fmaxf(mx[2], mx[6]); mx[3] = fmaxf(mx[3], mx[7]);
                mx[0] = fmaxf(mx[0], mx[2]); mx[1] = fmaxf(mx[1], mx[3]);
                float pmax;
                {
                    float2 sw = swap32(fmaxf(mx[0], mx[1]));
                    pmax = fmaxf(sw.x, sw.y);
                }

                // defer-max (T13): only rescale when the row max grew by > 8 (log2 domain)
                unsigned long long need = __ballot(pmax > mrun + 8.0f);
                float fc = 1.0f;
                if (need) {
                    float nm = fmaxf(mrun, pmax);
                    fc = exp2f(mrun - nm);
                    mrun = nm;
                }
#pragma unroll
                for (int r = 0; r < 16; ++r) {
                    sc0[r] = exp2f(sc0[r] - mrun);
                    sc1[r] = exp2f(sc1[r] - mrun);
                }
                // tree sum + cross-half
                float sm[8];
#pragma unroll
                for (int r = 0; r < 8; ++r)
                    sm[r] = (sc0[r] + sc0[r + 8]) + (sc1[r] + sc1[r + 8]);
                sm[0] += sm[4]; sm[1] += sm[5]; sm[2] += sm[6]; sm[3] += sm[7];
                sm[0] += sm[2]; sm[1] += sm[3];
                float ps;
                {
                    float2 sw = swap32(sm[0] + sm[1]);
                    ps = sw.x + sw.y;
                }
                if (need) {
                    lsum = lsum * fc + ps;
#pragma unroll
                    for (int i = 0; i < 16; ++i) { accO0[i] *= fc; accO1[i] *= fc; }
                } else {
                    lsum += ps;
                }

                // pack P -> bf16 B-fragments via cvt_pk + permlane32_swap (no LDS)
                bf16x8 pf[4];
#pragma unroll
                for (int c = 0; c < 4; ++c) {
                    const int bb = (c & 1) * 8;
                    float s0, s1, s2, s3, s4, s5, s6, s7;
                    if (c < 2) {
                        s0 = sc0[bb + 0]; s1 = sc0[bb + 1]; s2 = sc0[bb + 2]; s3 = sc0[bb + 3];
                        s4 = sc0[bb + 4]; s5 = sc0[bb + 5]; s6 = sc0[bb + 6]; s7 = sc0[bb + 7];
                    } else {
                        s0 = sc1[bb + 0]; s1 = sc1[bb + 1]; s2 = sc1[bb + 2]; s3 = sc1[bb + 3];
                        s4 = sc1[bb + 4]; s5 = sc1[bb + 5]; s6 = sc1[bb + 6]; s7 = sc1[bb + 7];
                    }
                    u32 A  = cvtpk(s0, s1);
                    u32 A2 = cvtpk(s2, s3);
                    u32 Bp = cvtpk(s4, s5);
                    u32 B2 = cvtpk(s6, s7);
                    u32x2 r02 = __builtin_amdgcn_permlane32_swap(A, Bp, 0, 0);
                    u32x2 r13 = __builtin_amdgcn_permlane32_swap(A2, B2, 0, 0);
                    union { u32 w[4]; bf16x8 v; } pu;
                    pu.w[0] = r02[0]; pu.w[1] = r13[0];
                    pu.w[2] = r02[1]; pu.w[3] = r13[1];
                    pf[c] = pu.v;
                }

                __builtin_amdgcn_s_setprio(1);
#pragma unroll
                for (int c = 0; c < 4; ++c) {
                    int u = ((c << 1) | hi) ^ (ln & 7);
                    bf16x8 vf0 = *(const bf16x8*)(sVb + ln * 64 + u * 8);
                    bf16x8 vf1 = *(const bf16x8*)(sVb + (32 + ln) * 64 + u * 8);
                    accO0 = __builtin_amdgcn_mfma_f32_32x32x16_bf16(vf0, pf[c], accO0, 0, 0, 0);
                    accO1 = __builtin_amdgcn_mfma_f32_32x32x16_bf16(vf1, pf[c], accO1, 0, 0, 0);
                }
                __builtin_amdgcn_s_setprio(0);
            }
            if (t + 2 < NT)      asm volatile("s_waitcnt vmcnt(4)" ::: "memory");
            else if (t + 1 < NT) asm volatile("s_waitcnt vmcnt(0)" ::: "memory");
            __syncthreads();
            cur = (cur == 2) ? 0 : cur + 1;
        }

        const float linv = 1.0f / lsum;
        u16* orow = Og + ((size_t)(b * TSEQ + qglob)) * DMODEL + h * HDIM;
#pragma unroll
        for (int a = 0; a < 4; ++a) {
            int d0 = 8 * a + 4 * hi;
            uint2 wo;
            wo.x = cvtpk(accO0[4 * a + 0] * linv, accO0[4 * a + 1] * linv);
            wo.y = cvtpk(accO0[4 * a + 2] * linv, accO0[4 * a + 3] * linv);
            *(uint2*)(orow + d0) = wo;
            wo.x = cvtpk(accO1[4 * a + 0] * linv, accO1[4 * a + 1] * linv);
            wo.y = cvtpk(accO1[4 * a + 2] * linv, accO1[4 * a + 3] * linv);
            *(uint2*)(orow + 32 + d0) = wo;
        }
    }
}

// ---------------- launch ----------------
extern "C" void kernel_launch(void* const* d_in, const int* in_sizes, int n_in,
                              void* d_out, int out_size, void* d_ws, size_t ws_size,
                              hipStream_t stream) {
    const float* x  = (const float*)d_in[0];
    const float* Wq = (const float*)d_in[1];
    const float* bq = (const float*)d_in[2];
    const float* Wk = (const float*)d_in[3];
    const float* bk = (const float*)d_in[4];
    const float* Wv = (const float*)d_in[5];
    const float* bv = (const float*)d_in[6];
    const float* Wo = (const float*)d_in[7];
    const float* bo = (const float*)d_in[8];
    float* out = (float*)d_out;

    u16* ws  = (u16*)d_ws;
    u16* xb  = ws;
    u16* WqT = xb  + (size_t)MTOT * DMODEL;
    u16* WkT = WqT + (size_t)DMODEL * DMODEL;
    u16* WvT = WkT + (size_t)DMODEL * DMODEL;
    u16* WoT = WvT + (size_t)DMODEL * DMODEL;
    u16* Qg  = WoT + (size_t)DMODEL * DMODEL;
    u16* Kg  = Qg  + (size_t)MTOT * DMODEL;
    u16* VTg = Kg  + (size_t)MTOT * DMODEL;
    u16* Og  = VTg + (size_t)MTOT * DMODEL;
    float* biasP = (float*)(Og + (size_t)MTOT * DMODEL);   // 3072 floats

    cvt_x<<<(MTOT * DMODEL) / (256 * 4), 256, 0, stream>>>(x, xb);
    dim3 tg(16, 16);
    wtrans<<<tg, 256, 0, stream>>>(Wq, WqT);
    wtrans<<<tg, 256, 0, stream>>>(Wk, WkT);
    wtrans<<<tg, 256, 0, stream>>>(Wv, WvT);
    wtrans<<<tg, 256, 0, stream>>>(Wo, WoT);
    pack_bias<<<12, 256, 0, stream>>>(bq, bk, bv, biasP);

    // fused QKV: N = 3072 (WqT|WkT|WvT contiguous)
    gemm_bt<0><<<dim3(24, MTOT / 128), 256, 0, stream>>>(xb, WqT, biasP,
                                                         Qg, Kg, VTg, nullptr, DMODEL);

    attn<<<dim3(64, 8), 256, 0, stream>>>(Qg, Kg, VTg, Og);

    gemm_bt<3><<<dim3(8, MTOT / 128), 256, 0, stream>>>(Og, WoT, bo,
                                                        nullptr, nullptr, nullptr, out, DMODEL);
}

// Round 7
// 263.620 us; speedup vs baseline: 1.2528x; 1.2528x over previous
//
#include <hip/hip_runtime.h>
#include <hip/hip_bf16.h>
#include <cmath>

#define TSEQ 2048
#define DMODEL 1024
#define NHEAD 16
#define HDIM 64
#define BATCH 4
#define MTOT (BATCH*TSEQ)   // 8192

typedef __attribute__((ext_vector_type(8))) short bf16x8;
typedef __attribute__((ext_vector_type(4))) float f32x4;
typedef __attribute__((ext_vector_type(16))) float f32x16;
typedef unsigned short u16;
typedef unsigned int u32;
typedef __attribute__((ext_vector_type(2))) unsigned int u32x2;

#define QSCALE 0.18033688011112042f   // 0.125 * log2(e)

__device__ __forceinline__ u16 f2bf(float f) {
    union { float f; unsigned u; } v; v.f = f;
    unsigned r = (v.u + 0x7fffu + ((v.u >> 16) & 1u)) >> 16;
    return (u16)r;
}

__device__ __forceinline__ u32 cvtpk(float a, float b) {
    u32 r;
    asm("v_cvt_pk_bf16_f32 %0, %1, %2" : "=v"(r) : "v"(a), "v"(b));
    return r;
}

// cross-half exchange: returns {v0,v1} with v0 op v1 == x op partner(x) on every lane
__device__ __forceinline__ float2 swap32(float x) {
    union { float f; u32 u; } a; a.f = x;
    u32x2 r = __builtin_amdgcn_permlane32_swap(a.u, a.u, 0, 0);
    union { u32 u; float f; } p, q;
    p.u = r[0]; q.u = r[1];
    return make_float2(p.f, q.f);
}

// async global->LDS, 16B per lane; LDS dest is wave-uniform base (+lane*16 by HW)
#define GLOAD16(g, s) __builtin_amdgcn_global_load_lds( \
    (const __attribute__((address_space(1))) void*)(g), \
    (__attribute__((address_space(3))) void*)(s), 16, 0, 0)

// ---------------- converters ----------------
__global__ __launch_bounds__(256) void cvt_x(const float* __restrict__ x,
                                             u16* __restrict__ xb) {
    int i = (blockIdx.x * 256 + threadIdx.x) * 4;
    float4 v = *(const float4*)(x + i);
    ushort4 o;
    o.x = f2bf(v.x); o.y = f2bf(v.y); o.z = f2bf(v.z); o.w = f2bf(v.w);
    *(ushort4*)(xb + i) = o;
}

// WT[n][k] = bf16(W[k][n]); 64x64 tiles
__global__ __launch_bounds__(256) void wtrans(const float* __restrict__ W,
                                              u16* __restrict__ WT) {
    __shared__ float tile[64][65];
    int n0 = blockIdx.x * 64, k0 = blockIdx.y * 64;
    int t = threadIdx.x;
    int r = t >> 4;
    int c4 = (t & 15) * 4;
#pragma unroll
    for (int rr = 0; rr < 4; rr++) {
        int k = rr * 16 + r;
        float4 v = *(const float4*)(W + (size_t)(k0 + k) * DMODEL + n0 + c4);
        tile[k][c4 + 0] = v.x; tile[k][c4 + 1] = v.y;
        tile[k][c4 + 2] = v.z; tile[k][c4 + 3] = v.w;
    }
    __syncthreads();
#pragma unroll
    for (int rr = 0; rr < 4; rr++) {
        int n = rr * 16 + r;
        ushort4 o;
        o.x = f2bf(tile[c4 + 0][n]);
        o.y = f2bf(tile[c4 + 1][n]);
        o.z = f2bf(tile[c4 + 2][n]);
        o.w = f2bf(tile[c4 + 3][n]);
        *(ushort4*)(WT + (size_t)(n0 + n) * DMODEL + k0 + c4) = o;
    }
}

__global__ __launch_bounds__(256) void pack_bias(const float* __restrict__ bq,
                                                 const float* __restrict__ bk,
                                                 const float* __restrict__ bv,
                                                 float* __restrict__ bp) {
    int i = blockIdx.x * 256 + threadIdx.x;   // 0..3071
    float v = (i < 1024) ? bq[i] * QSCALE : (i < 2048) ? bk[i - 1024] : bv[i - 2048];
    bp[i] = v;
}

// ---------------- GEMM: 128x128 tile, BK=32, 3-buffer counted-vmcnt pipeline ----------------
// MODE 0: fused QKV (N=3072): seg0->Qg (pre-scaled by QSCALE), seg1->Kg, seg2->VTg
// MODE 3: f32 out [M][N]
template<int MODE>
__global__ __launch_bounds__(256) void gemm_bt(const u16* __restrict__ A,
                                               const u16* __restrict__ BT,
                                               const float* __restrict__ bias,
                                               u16* __restrict__ Qg,
                                               u16* __restrict__ Kg,
                                               u16* __restrict__ VTg,
                                               float* __restrict__ Fout,
                                               int K) {
    __shared__ __align__(16) u16 lds[6 * 4096];   // lA bufs 0..2, lB bufs 0..2 (48 KB)
    // XCD-chunked swizzle (nwg multiple of 8)
    int nwg = gridDim.x * gridDim.y;
    int bid = blockIdx.y * gridDim.x + blockIdx.x;
    int cpx = nwg >> 3;
    int swz = (bid & 7) * cpx + (bid >> 3);
    int bx = swz % gridDim.x, by = swz / gridDim.x;
    int m0 = by * 128, n0 = bx * 128;
    int t = threadIdx.x, l = t & 63, w = t >> 6;
    int wr = w >> 1, wc = w & 1;
    int lg = l >> 4, lr = l & 15;
    f32x4 acc[4][4];
#pragma unroll
    for (int i = 0; i < 4; i++)
#pragma unroll
        for (int j = 0; j < 4; j++) acc[i][j] = (f32x4){0.f, 0.f, 0.f, 0.f};

    auto STAGE = [&](int kt, int nbuf) {
        int k0 = kt << 5;
#pragma unroll
        for (int s = 0; s < 2; ++s) {
            int cc = t + s * 256;
            int row = cc >> 2, ko = (cc & 3) * 8;
            GLOAD16(A  + (size_t)(m0 + row) * K + k0 + ko,
                    lds + nbuf * 4096 + (s * 256 + w * 64) * 8);
            GLOAD16(BT + (size_t)(n0 + row) * K + k0 + ko,
                    lds + 12288 + nbuf * 4096 + (s * 256 + w * 64) * 8);
        }
    };

    const int KT = K >> 5;
    STAGE(0, 0);
    STAGE(1, 1);
    asm volatile("s_waitcnt vmcnt(4)" ::: "memory");
    __syncthreads();
    int cur = 0;
    for (int kt = 0; kt < KT; ++kt) {
        int sb = cur + 2; if (sb >= 3) sb -= 3;
        if (kt + 2 < KT) STAGE(kt + 2, sb);
        const u16* a_ = lds + cur * 4096;
        const u16* b_ = lds + 12288 + cur * 4096;
        bf16x8 af[4], bfr[4];
#pragma unroll
        for (int i = 0; i < 4; i++) {
            af[i]  = *(const bf16x8*)(a_ + (wr * 64 + i * 16 + lr) * 32 + lg * 8);
            bfr[i] = *(const bf16x8*)(b_ + (wc * 64 + i * 16 + lr) * 32 + lg * 8);
        }
        __builtin_amdgcn_s_setprio(1);
#pragma unroll
        for (int mi = 0; mi < 4; mi++)
#pragma unroll
            for (int ni = 0; ni < 4; ni++)
                acc[mi][ni] = __builtin_amdgcn_mfma_f32_16x16x32_bf16(
                    af[mi], bfr[ni], acc[mi][ni], 0, 0, 0);
        __builtin_amdgcn_s_setprio(0);
        if (kt + 2 < KT)      asm volatile("s_waitcnt vmcnt(4)" ::: "memory");
        else if (kt + 1 < KT) asm volatile("s_waitcnt vmcnt(0)" ::: "memory");
        __syncthreads();
        cur = (cur == 2) ? 0 : cur + 1;
    }

    if (MODE == 0) {
        int seg = n0 >> 10;                       // block-uniform
        float ss = (seg == 0) ? QSCALE : 1.0f;
        u16* outb = (seg == 0) ? Qg : (seg == 1) ? Kg : VTg;
#pragma unroll
        for (int mi = 0; mi < 4; mi++)
#pragma unroll
            for (int ni = 0; ni < 4; ni++) {
                int ng = n0 + wc * 64 + ni * 16 + lr;
                int ngl = ng & 1023;
                int h = ngl >> 6, d = ngl & 63;
                int mg0 = m0 + wr * 64 + mi * 16 + lg * 4;
                int bb = mg0 >> 11, tq0 = mg0 & 2047;
                float bsv = bias[ng];
                if (seg == 2) {
                    ushort4 o;
                    o.x = f2bf(acc[mi][ni][0] + bsv);
                    o.y = f2bf(acc[mi][ni][1] + bsv);
                    o.z = f2bf(acc[mi][ni][2] + bsv);
                    o.w = f2bf(acc[mi][ni][3] + bsv);
                    *(ushort4*)&VTg[(((size_t)(bb * NHEAD + h)) * HDIM + d) * TSEQ + tq0] = o;
                } else {
#pragma unroll
                    for (int r = 0; r < 4; r++) {
                        float v = acc[mi][ni][r] * ss + bsv;
                        outb[(((size_t)(bb * NHEAD + h)) * TSEQ + tq0 + r) * HDIM + d] = f2bf(v);
                    }
                }
            }
    } else {
#pragma unroll
        for (int mi = 0; mi < 4; mi++)
#pragma unroll
            for (int ni = 0; ni < 4; ni++) {
                int ng = n0 + wc * 64 + ni * 16 + lr;
                int mg0 = m0 + wr * 64 + mi * 16 + lg * 4;
                float bsv = bias[ng];
#pragma unroll
                for (int r = 0; r < 4; r++)
                    Fout[(size_t)(mg0 + r) * DMODEL + ng] = acc[mi][ni][r] + bsv;
            }
    }
}

// ---------------- flash attention: 32x32 swapped, in-register softmax ----------------
// Q: [bh][T][64] bf16 pre-scaled by QSCALE; K: [bh][T][64]; VT: [bh][64][T]; O: [M][D] bf16
// Single-pass blocks: grid (64 bh, 16 q-supers of 128 rows), 4 waves x 32 q-rows.
// sidx permutation balances causal work across presumed CU id-quartets {y,y+4,y+8,y+12}.
__global__ __launch_bounds__(256, 4) void attn(const u16* __restrict__ Qg,
                                               const u16* __restrict__ Kg,
                                               const u16* __restrict__ VTg,
                                               u16* __restrict__ Og) {
    __shared__ __align__(16) u16 sK[2 * 4096];
    __shared__ __align__(16) u16 sV[2 * 4096];
    const int bh = blockIdx.x;       // 0..63  (stride-64 ids -> same XCD per bh)
    const int y  = blockIdx.y;       // 0..15
    const int kq = y & 3, jq = y >> 2;
    const int sidx = (jq == 0) ? 15 - kq
                   : (jq == 1) ? 8 + kq
                   : (jq == 2) ? 4 + ((6 - kq) & 3)
                   : ((kq + 1) & 3);
    const int tid = threadIdx.x;
    const int wv = tid >> 6;
    const int l  = tid & 63;
    const int ln = l & 31;
    const int hi = l >> 5;
    const int b = bh >> 4, h = bh & 15;

    auto STAGE = [&](int tt, int nbuf) {
        int kv0s = tt << 6;
#pragma unroll
        for (int s = 0; s < 2; ++s) {
            int cc = tid + s * 256;
            int row = cc >> 3, c = cc & 7;
            int csrc = c ^ (row & 7);
            GLOAD16(Kg + ((size_t)bh * TSEQ + kv0s + row) * HDIM + csrc * 8,
                    sK + nbuf * 4096 + (s * 256 + wv * 64) * 8);
            GLOAD16(VTg + ((size_t)bh * HDIM + row) * TSEQ + kv0s + csrc * 8,
                    sV + nbuf * 4096 + (s * 256 + wv * 64) * 8);
        }
    };

    const int qs = sidx << 7;
    const int NT = (qs >> 6) + 2;            // 2*sidx + 2
    const int q0w = qs + wv * 32;
    const int qglob = q0w + ln;

    bf16x8 qf0, qf1, qf2, qf3;
    {
        const u16* qb = Qg + ((size_t)bh * TSEQ + qglob) * HDIM + hi * 8;
        qf0 = *(const bf16x8*)(qb);
        qf1 = *(const bf16x8*)(qb + 16);
        qf2 = *(const bf16x8*)(qb + 32);
        qf3 = *(const bf16x8*)(qb + 48);
    }
    float mrun = -INFINITY, lsum = 0.f;
    f32x16 accO0, accO1;
#pragma unroll
    for (int i = 0; i < 16; ++i) { accO0[i] = 0.f; accO1[i] = 0.f; }

    int nb = 0;
    STAGE(0, 0);
    asm volatile("s_waitcnt vmcnt(0)" ::: "memory");
    __syncthreads();

    for (int t = 0; t < NT; ++t) {
        if (t + 1 < NT) STAGE(t + 1, nb ^ 1);
        const int kv0 = t << 6;
        if (kv0 <= q0w + 31) {          // wave-uniform active check
            const u16* sKb = sK + nb * 4096;
            const u16* sVb = sV + nb * 4096;
            f32x16 sc0, sc1;
#pragma unroll
            for (int i = 0; i < 16; ++i) { sc0[i] = 0.f; sc1[i] = 0.f; }
            __builtin_amdgcn_s_setprio(1);
#pragma unroll
            for (int c = 0; c < 4; ++c) {
                int u = ((c << 1) | hi) ^ (ln & 7);
                bf16x8 kf0 = *(const bf16x8*)(sKb + ln * 64 + u * 8);
                bf16x8 kf1 = *(const bf16x8*)(sKb + (32 + ln) * 64 + u * 8);
                bf16x8 qq = (c == 0) ? qf0 : (c == 1) ? qf1 : (c == 2) ? qf2 : qf3;
                sc0 = __builtin_amdgcn_mfma_f32_32x32x16_bf16(kf0, qq, sc0, 0, 0, 0);
                sc1 = __builtin_amdgcn_mfma_f32_32x32x16_bf16(kf1, qq, sc1, 0, 0, 0);
            }
            __builtin_amdgcn_s_setprio(0);

            if (kv0 + 63 > q0w) {       // diagonal tile: apply causal mask
                const int qrel = qglob - kv0;
#pragma unroll
                for (int r = 0; r < 16; ++r) {
                    int e0 = (r & 3) + 8 * (r >> 2) + 4 * hi;
                    if (e0 > qrel) sc0[r] = -INFINITY;
                    if (e0 + 32 > qrel) sc1[r] = -INFINITY;
                }
            }

            // tree max over the lane's 32 values, then cross-half via permlane
            float mx[8];
#pragma unroll
            for (int r = 0; r < 8; ++r)
                mx[r] = fmaxf(fmaxf(sc0[r], sc0[r + 8]), fmaxf(sc1[r], sc1[r + 8]));
            mx[0] = fmaxf(mx[0], mx[4]); mx[1] = fmaxf(mx[1], mx[5]);
            mx[2] = fmaxf(mx[2], mx[6]); mx[3] = fmaxf(mx[3], mx[7]);
            mx[0] = fmaxf(mx[0], mx[2]); mx[1] = fmaxf(mx[1], mx[3]);
            float pmax;
            {
                float2 sw = swap32(fmaxf(mx[0], mx[1]));
                pmax = fmaxf(sw.x, sw.y);
            }

            // defer-max (T13): only rescale when the row max grew by > 8 (log2 domain)
            unsigned long long need = __ballot(pmax > mrun + 8.0f);
            float fc = 1.0f;
            if (need) {
                float nm = fmaxf(mrun, pmax);
                fc = exp2f(mrun - nm);
                mrun = nm;
            }
#pragma unroll
            for (int r = 0; r < 16; ++r) {
                sc0[r] = exp2f(sc0[r] - mrun);
                sc1[r] = exp2f(sc1[r] - mrun);
            }
            // tree sum + cross-half
            float sm[8];
#pragma unroll
            for (int r = 0; r < 8; ++r)
                sm[r] = (sc0[r] + sc0[r + 8]) + (sc1[r] + sc1[r + 8]);
            sm[0] += sm[4]; sm[1] += sm[5]; sm[2] += sm[6]; sm[3] += sm[7];
            sm[0] += sm[2]; sm[1] += sm[3];
            float ps;
            {
                float2 sw = swap32(sm[0] + sm[1]);
                ps = sw.x + sw.y;
            }
            if (need) {
                lsum = lsum * fc + ps;
#pragma unroll
                for (int i = 0; i < 16; ++i) { accO0[i] *= fc; accO1[i] *= fc; }
            } else {
                lsum += ps;
            }

            // pack P -> bf16 B-fragments via cvt_pk + permlane32_swap (no LDS)
            bf16x8 pf[4];
#pragma unroll
            for (int c = 0; c < 4; ++c) {
                const int bb = (c & 1) * 8;
                float s0, s1, s2, s3, s4, s5, s6, s7;
                if (c < 2) {
                    s0 = sc0[bb + 0]; s1 = sc0[bb + 1]; s2 = sc0[bb + 2]; s3 = sc0[bb + 3];
                    s4 = sc0[bb + 4]; s5 = sc0[bb + 5]; s6 = sc0[bb + 6]; s7 = sc0[bb + 7];
                } else {
                    s0 = sc1[bb + 0]; s1 = sc1[bb + 1]; s2 = sc1[bb + 2]; s3 = sc1[bb + 3];
                    s4 = sc1[bb + 4]; s5 = sc1[bb + 5]; s6 = sc1[bb + 6]; s7 = sc1[bb + 7];
                }
                u32 A  = cvtpk(s0, s1);
                u32 A2 = cvtpk(s2, s3);
                u32 Bp = cvtpk(s4, s5);
                u32 B2 = cvtpk(s6, s7);
                u32x2 r02 = __builtin_amdgcn_permlane32_swap(A, Bp, 0, 0);
                u32x2 r13 = __builtin_amdgcn_permlane32_swap(A2, B2, 0, 0);
                union { u32 w[4]; bf16x8 v; } pu;
                pu.w[0] = r02[0]; pu.w[1] = r13[0];
                pu.w[2] = r02[1]; pu.w[3] = r13[1];
                pf[c] = pu.v;
            }

            __builtin_amdgcn_s_setprio(1);
#pragma unroll
            for (int c = 0; c < 4; ++c) {
                int u = ((c << 1) | hi) ^ (ln & 7);
                bf16x8 vf0 = *(const bf16x8*)(sVb + ln * 64 + u * 8);
                bf16x8 vf1 = *(const bf16x8*)(sVb + (32 + ln) * 64 + u * 8);
                accO0 = __builtin_amdgcn_mfma_f32_32x32x16_bf16(vf0, pf[c], accO0, 0, 0, 0);
                accO1 = __builtin_amdgcn_mfma_f32_32x32x16_bf16(vf1, pf[c], accO1, 0, 0, 0);
            }
            __builtin_amdgcn_s_setprio(0);
        }
        asm volatile("s_waitcnt vmcnt(0)" ::: "memory");
        __syncthreads();
        nb ^= 1;
    }

    const float linv = 1.0f / lsum;
    u16* orow = Og + ((size_t)(b * TSEQ + qglob)) * DMODEL + h * HDIM;
#pragma unroll
    for (int a = 0; a < 4; ++a) {
        int d0 = 8 * a + 4 * hi;
        uint2 wo;
        wo.x = cvtpk(accO0[4 * a + 0] * linv, accO0[4 * a + 1] * linv);
        wo.y = cvtpk(accO0[4 * a + 2] * linv, accO0[4 * a + 3] * linv);
        *(uint2*)(orow + d0) = wo;
        wo.x = cvtpk(accO1[4 * a + 0] * linv, accO1[4 * a + 1] * linv);
        wo.y = cvtpk(accO1[4 * a + 2] * linv, accO1[4 * a + 3] * linv);
        *(uint2*)(orow + 32 + d0) = wo;
    }
}

// ---------------- launch ----------------
extern "C" void kernel_launch(void* const* d_in, const int* in_sizes, int n_in,
                              void* d_out, int out_size, void* d_ws, size_t ws_size,
                              hipStream_t stream) {
    const float* x  = (const float*)d_in[0];
    const float* Wq = (const float*)d_in[1];
    const float* bq = (const float*)d_in[2];
    const float* Wk = (const float*)d_in[3];
    const float* bk = (const float*)d_in[4];
    const float* Wv = (const float*)d_in[5];
    const float* bv = (const float*)d_in[6];
    const float* Wo = (const float*)d_in[7];
    const float* bo = (const float*)d_in[8];
    float* out = (float*)d_out;

    u16* ws  = (u16*)d_ws;
    u16* xb  = ws;
    u16* WqT = xb  + (size_t)MTOT * DMODEL;
    u16* WkT = WqT + (size_t)DMODEL * DMODEL;
    u16* WvT = WkT + (size_t)DMODEL * DMODEL;
    u16* WoT = WvT + (size_t)DMODEL * DMODEL;
    u16* Qg  = WoT + (size_t)DMODEL * DMODEL;
    u16* Kg  = Qg  + (size_t)MTOT * DMODEL;
    u16* VTg = Kg  + (size_t)MTOT * DMODEL;
    u16* Og  = VTg + (size_t)MTOT * DMODEL;
    float* biasP = (float*)(Og + (size_t)MTOT * DMODEL);   // 3072 floats

    cvt_x<<<(MTOT * DMODEL) / (256 * 4), 256, 0, stream>>>(x, xb);
    dim3 tg(16, 16);
    wtrans<<<tg, 256, 0, stream>>>(Wq, WqT);
    wtrans<<<tg, 256, 0, stream>>>(Wk, WkT);
    wtrans<<<tg, 256, 0, stream>>>(Wv, WvT);
    wtrans<<<tg, 256, 0, stream>>>(Wo, WoT);
    pack_bias<<<12, 256, 0, stream>>>(bq, bk, bv, biasP);

    // fused QKV: N = 3072 (WqT|WkT|WvT contiguous)
    gemm_bt<0><<<dim3(24, MTOT / 128), 256, 0, stream>>>(xb, WqT, biasP,
                                                         Qg, Kg, VTg, nullptr, DMODEL);

    attn<<<dim3(64, 16), 256, 0, stream>>>(Qg, Kg, VTg, Og);

    gemm_bt<3><<<dim3(8, MTOT / 128), 256, 0, stream>>>(Og, WoT, bo,
                                                        nullptr, nullptr, nullptr, out, DMODEL);
}

// Round 8
// 256.168 us; speedup vs baseline: 1.2893x; 1.0291x over previous
//
#include <hip/hip_runtime.h>
#include <hip/hip_bf16.h>
#include <cmath>

#define TSEQ 2048
#define DMODEL 1024
#define NHEAD 16
#define HDIM 64
#define BATCH 4
#define MTOT (BATCH*TSEQ)   // 8192

typedef __attribute__((ext_vector_type(8))) short bf16x8;
typedef __attribute__((ext_vector_type(4))) float f32x4;
typedef __attribute__((ext_vector_type(16))) float f32x16;
typedef unsigned short u16;
typedef unsigned int u32;
typedef __attribute__((ext_vector_type(2))) unsigned int u32x2;

#define QSCALE 0.18033688011112042f   // 0.125 * log2(e)

__device__ __forceinline__ u16 f2bf(float f) {
    union { float f; unsigned u; } v; v.f = f;
    unsigned r = (v.u + 0x7fffu + ((v.u >> 16) & 1u)) >> 16;
    return (u16)r;
}

__device__ __forceinline__ u32 cvtpk(float a, float b) {
    u32 r;
    asm("v_cvt_pk_bf16_f32 %0, %1, %2" : "=v"(r) : "v"(a), "v"(b));
    return r;
}

// cross-half exchange: returns {v0,v1} with v0 op v1 == x op partner(x) on every lane
__device__ __forceinline__ float2 swap32(float x) {
    union { float f; u32 u; } a; a.f = x;
    u32x2 r = __builtin_amdgcn_permlane32_swap(a.u, a.u, 0, 0);
    union { u32 u; float f; } p, q;
    p.u = r[0]; q.u = r[1];
    return make_float2(p.f, q.f);
}

// async global->LDS, 16B per lane; LDS dest is wave-uniform base (+lane*16 by HW)
#define GLOAD16(g, s) __builtin_amdgcn_global_load_lds( \
    (const __attribute__((address_space(1))) void*)(g), \
    (__attribute__((address_space(3))) void*)(s), 16, 0, 0)

// ---------------- fused prep: x->bf16, 4 weight transposes, bias pack ----------------
// grid: [0,4096) cvt x (8 elems/thread); [4096,5120) wtrans (4 x 256 tiles); [5120,5132) bias
__global__ __launch_bounds__(256) void prep(const float* __restrict__ x,
                                            const float* __restrict__ Wq,
                                            const float* __restrict__ Wk,
                                            const float* __restrict__ Wv,
                                            const float* __restrict__ Wo,
                                            const float* __restrict__ bq,
                                            const float* __restrict__ bk,
                                            const float* __restrict__ bv,
                                            u16* __restrict__ xb,
                                            u16* __restrict__ WqT,
                                            u16* __restrict__ WkT,
                                            u16* __restrict__ WvT,
                                            u16* __restrict__ WoT,
                                            float* __restrict__ biasP) {
    __shared__ float tile[64][65];
    const int bid = blockIdx.x, t = threadIdx.x;
    if (bid < 4096) {
        size_t i = ((size_t)bid * 256 + t) * 8;
        float4 v0 = *(const float4*)(x + i);
        float4 v1 = *(const float4*)(x + i + 4);
        ushort4 o0, o1;
        o0.x = f2bf(v0.x); o0.y = f2bf(v0.y); o0.z = f2bf(v0.z); o0.w = f2bf(v0.w);
        o1.x = f2bf(v1.x); o1.y = f2bf(v1.y); o1.z = f2bf(v1.z); o1.w = f2bf(v1.w);
        *(ushort4*)(xb + i) = o0;
        *(ushort4*)(xb + i + 4) = o1;
    } else if (bid < 5120) {
        const int wsel = (bid - 4096) >> 8;
        const int tb   = (bid - 4096) & 255;
        const float* W = (wsel == 0) ? Wq : (wsel == 1) ? Wk : (wsel == 2) ? Wv : Wo;
        u16* WT        = (wsel == 0) ? WqT : (wsel == 1) ? WkT : (wsel == 2) ? WvT : WoT;
        const int n0 = (tb & 15) * 64, k0 = (tb >> 4) * 64;
        const int r = t >> 4;
        const int c4 = (t & 15) * 4;
#pragma unroll
        for (int rr = 0; rr < 4; rr++) {
            int k = rr * 16 + r;
            float4 v = *(const float4*)(W + (size_t)(k0 + k) * DMODEL + n0 + c4);
            tile[k][c4 + 0] = v.x; tile[k][c4 + 1] = v.y;
            tile[k][c4 + 2] = v.z; tile[k][c4 + 3] = v.w;
        }
        __syncthreads();
#pragma unroll
        for (int rr = 0; rr < 4; rr++) {
            int n = rr * 16 + r;
            ushort4 o;
            o.x = f2bf(tile[c4 + 0][n]);
            o.y = f2bf(tile[c4 + 1][n]);
            o.z = f2bf(tile[c4 + 2][n]);
            o.w = f2bf(tile[c4 + 3][n]);
            *(ushort4*)(WT + (size_t)(n0 + n) * DMODEL + k0 + c4) = o;
        }
    } else {
        int i = (bid - 5120) * 256 + t;   // 0..3071
        float v = (i < 1024) ? bq[i] * QSCALE : (i < 2048) ? bk[i - 1024] : bv[i - 2048];
        biasP[i] = v;
    }
}

// ---------------- GEMM: 128x128 tile, BK=32, 3-buffer counted-vmcnt pipeline ----------------
// MODE 0: fused QKV (N=3072): seg0->Qg (pre-scaled by QSCALE), seg1->Kg, seg2->VTg
// MODE 3: f32 out [M][N]
template<int MODE>
__global__ __launch_bounds__(256) void gemm_bt(const u16* __restrict__ A,
                                               const u16* __restrict__ BT,
                                               const float* __restrict__ bias,
                                               u16* __restrict__ Qg,
                                               u16* __restrict__ Kg,
                                               u16* __restrict__ VTg,
                                               float* __restrict__ Fout,
                                               int K) {
    __shared__ __align__(16) u16 lds[6 * 4096];   // lA bufs 0..2, lB bufs 0..2 (48 KB)
    // XCD-chunked swizzle (nwg multiple of 8)
    int nwg = gridDim.x * gridDim.y;
    int bid = blockIdx.y * gridDim.x + blockIdx.x;
    int cpx = nwg >> 3;
    int swz = (bid & 7) * cpx + (bid >> 3);
    int bx = swz % gridDim.x, by = swz / gridDim.x;
    int m0 = by * 128, n0 = bx * 128;
    int t = threadIdx.x, l = t & 63, w = t >> 6;
    int wr = w >> 1, wc = w & 1;
    int lg = l >> 4, lr = l & 15;
    f32x4 acc[4][4];
#pragma unroll
    for (int i = 0; i < 4; i++)
#pragma unroll
        for (int j = 0; j < 4; j++) acc[i][j] = (f32x4){0.f, 0.f, 0.f, 0.f};

    auto STAGE = [&](int kt, int nbuf) {
        int k0 = kt << 5;
#pragma unroll
        for (int s = 0; s < 2; ++s) {
            int cc = t + s * 256;
            int row = cc >> 2, ko = (cc & 3) * 8;
            GLOAD16(A  + (size_t)(m0 + row) * K + k0 + ko,
                    lds + nbuf * 4096 + (s * 256 + w * 64) * 8);
            GLOAD16(BT + (size_t)(n0 + row) * K + k0 + ko,
                    lds + 12288 + nbuf * 4096 + (s * 256 + w * 64) * 8);
        }
    };

    const int KT = K >> 5;
    STAGE(0, 0);
    STAGE(1, 1);
    asm volatile("s_waitcnt vmcnt(4)" ::: "memory");
    __syncthreads();
    int cur = 0;
    for (int kt = 0; kt < KT; ++kt) {
        int sb = cur + 2; if (sb >= 3) sb -= 3;
        if (kt + 2 < KT) STAGE(kt + 2, sb);
        const u16* a_ = lds + cur * 4096;
        const u16* b_ = lds + 12288 + cur * 4096;
        bf16x8 af[4], bfr[4];
#pragma unroll
        for (int i = 0; i < 4; i++) {
            af[i]  = *(const bf16x8*)(a_ + (wr * 64 + i * 16 + lr) * 32 + lg * 8);
            bfr[i] = *(const bf16x8*)(b_ + (wc * 64 + i * 16 + lr) * 32 + lg * 8);
        }
        __builtin_amdgcn_s_setprio(1);
#pragma unroll
        for (int mi = 0; mi < 4; mi++)
#pragma unroll
            for (int ni = 0; ni < 4; ni++)
                acc[mi][ni] = __builtin_amdgcn_mfma_f32_16x16x32_bf16(
                    af[mi], bfr[ni], acc[mi][ni], 0, 0, 0);
        __builtin_amdgcn_s_setprio(0);
        if (kt + 2 < KT)      asm volatile("s_waitcnt vmcnt(4)" ::: "memory");
        else if (kt + 1 < KT) asm volatile("s_waitcnt vmcnt(0)" ::: "memory");
        __syncthreads();
        cur = (cur == 2) ? 0 : cur + 1;
    }

    if (MODE == 0) {
        int seg = n0 >> 10;                       // block-uniform
        float ss = (seg == 0) ? QSCALE : 1.0f;
        u16* outb = (seg == 0) ? Qg : (seg == 1) ? Kg : VTg;
#pragma unroll
        for (int mi = 0; mi < 4; mi++)
#pragma unroll
            for (int ni = 0; ni < 4; ni++) {
                int ng = n0 + wc * 64 + ni * 16 + lr;
                int ngl = ng & 1023;
                int h = ngl >> 6, d = ngl & 63;
                int mg0 = m0 + wr * 64 + mi * 16 + lg * 4;
                int bb = mg0 >> 11, tq0 = mg0 & 2047;
                float bsv = bias[ng];
                if (seg == 2) {
                    ushort4 o;
                    o.x = f2bf(acc[mi][ni][0] + bsv);
                    o.y = f2bf(acc[mi][ni][1] + bsv);
                    o.z = f2bf(acc[mi][ni][2] + bsv);
                    o.w = f2bf(acc[mi][ni][3] + bsv);
                    *(ushort4*)&VTg[(((size_t)(bb * NHEAD + h)) * HDIM + d) * TSEQ + tq0] = o;
                } else {
#pragma unroll
                    for (int r = 0; r < 4; r++) {
                        float v = acc[mi][ni][r] * ss + bsv;
                        outb[(((size_t)(bb * NHEAD + h)) * TSEQ + tq0 + r) * HDIM + d] = f2bf(v);
                    }
                }
            }
    } else {
#pragma unroll
        for (int mi = 0; mi < 4; mi++)
#pragma unroll
            for (int ni = 0; ni < 4; ni++) {
                int ng = n0 + wc * 64 + ni * 16 + lr;
                int mg0 = m0 + wr * 64 + mi * 16 + lg * 4;
                float bsv = bias[ng];
#pragma unroll
                for (int r = 0; r < 4; r++)
                    Fout[(size_t)(mg0 + r) * DMODEL + ng] = acc[mi][ni][r] + bsv;
            }
    }
}

// ---------------- flash attention: 32x32 swapped, in-register softmax ----------------
// Q: [bh][T][64] bf16 pre-scaled by QSCALE; K: [bh][T][64]; VT: [bh][64][T]; O: [M][D] bf16
// Single-pass blocks: grid (64 bh, 16 q-supers of 128 rows), 4 waves x 32 q-rows.
// sidx permutation balances causal work across presumed CU id-quartets {y,y+4,y+8,y+12}.
__global__ __launch_bounds__(256, 4) void attn(const u16* __restrict__ Qg,
                                               const u16* __restrict__ Kg,
                                               const u16* __restrict__ VTg,
                                               u16* __restrict__ Og) {
    __shared__ __align__(16) u16 sK[2 * 4096];
    __shared__ __align__(16) u16 sV[2 * 4096];
    const int bh = blockIdx.x;       // 0..63  (stride-64 ids -> same XCD per bh)
    const int y  = blockIdx.y;       // 0..15
    const int kq = y & 3, jq = y >> 2;
    const int sidx = (jq == 0) ? 15 - kq
                   : (jq == 1) ? 8 + kq
                   : (jq == 2) ? 4 + ((6 - kq) & 3)
                   : ((kq + 1) & 3);
    const int tid = threadIdx.x;
    const int wv = tid >> 6;
    const int l  = tid & 63;
    const int ln = l & 31;
    const int hi = l >> 5;
    const int b = bh >> 4, h = bh & 15;

    auto STAGE = [&](int tt, int nbuf) {
        int kv0s = tt << 6;
#pragma unroll
        for (int s = 0; s < 2; ++s) {
            int cc = tid + s * 256;
            int row = cc >> 3, c = cc & 7;
            int csrc = c ^ (row & 7);
            GLOAD16(Kg + ((size_t)bh * TSEQ + kv0s + row) * HDIM + csrc * 8,
                    sK + nbuf * 4096 + (s * 256 + wv * 64) * 8);
            GLOAD16(VTg + ((size_t)bh * HDIM + row) * TSEQ + kv0s + csrc * 8,
                    sV + nbuf * 4096 + (s * 256 + wv * 64) * 8);
        }
    };

    const int qs = sidx << 7;
    const int NT = (qs >> 6) + 2;            // 2*sidx + 2
    const int q0w = qs + wv * 32;
    const int qglob = q0w + ln;

    bf16x8 qf0, qf1, qf2, qf3;
    {
        const u16* qb = Qg + ((size_t)bh * TSEQ + qglob) * HDIM + hi * 8;
        qf0 = *(const bf16x8*)(qb);
        qf1 = *(const bf16x8*)(qb + 16);
        qf2 = *(const bf16x8*)(qb + 32);
        qf3 = *(const bf16x8*)(qb + 48);
    }
    float mrun = -INFINITY, lsum = 0.f;
    f32x16 accO0, accO1;
#pragma unroll
    for (int i = 0; i < 16; ++i) { accO0[i] = 0.f; accO1[i] = 0.f; }

    int nb = 0;
    STAGE(0, 0);
    asm volatile("s_waitcnt vmcnt(0)" ::: "memory");
    __syncthreads();

    for (int t = 0; t < NT; ++t) {
        if (t + 1 < NT) STAGE(t + 1, nb ^ 1);
        const int kv0 = t << 6;
        if (kv0 <= q0w + 31) {          // wave-uniform active check
            const u16* sKb = sK + nb * 4096;
            const u16* sVb = sV + nb * 4096;
            f32x16 sc0, sc1;
#pragma unroll
            for (int i = 0; i < 16; ++i) { sc0[i] = 0.f; sc1[i] = 0.f; }
            __builtin_amdgcn_s_setprio(1);
#pragma unroll
            for (int c = 0; c < 4; ++c) {
                int u = ((c << 1) | hi) ^ (ln & 7);
                bf16x8 kf0 = *(const bf16x8*)(sKb + ln * 64 + u * 8);
                bf16x8 kf1 = *(const bf16x8*)(sKb + (32 + ln) * 64 + u * 8);
                bf16x8 qq = (c == 0) ? qf0 : (c == 1) ? qf1 : (c == 2) ? qf2 : qf3;
                sc0 = __builtin_amdgcn_mfma_f32_32x32x16_bf16(kf0, qq, sc0, 0, 0, 0);
                sc1 = __builtin_amdgcn_mfma_f32_32x32x16_bf16(kf1, qq, sc1, 0, 0, 0);
            }
            __builtin_amdgcn_s_setprio(0);

            if (kv0 + 63 > q0w) {       // diagonal tile: apply causal mask
                const int qrel = qglob - kv0;
#pragma unroll
                for (int r = 0; r < 16; ++r) {
                    int e0 = (r & 3) + 8 * (r >> 2) + 4 * hi;
                    if (e0 > qrel) sc0[r] = -INFINITY;
                    if (e0 + 32 > qrel) sc1[r] = -INFINITY;
                }
            }

            // tree max over the lane's 32 values, then cross-half via permlane
            float mx[8];
#pragma unroll
            for (int r = 0; r < 8; ++r)
                mx[r] = fmaxf(fmaxf(sc0[r], sc0[r + 8]), fmaxf(sc1[r], sc1[r + 8]));
            mx[0] = fmaxf(mx[0], mx[4]); mx[1] = fmaxf(mx[1], mx[5]);
            mx[2] = fmaxf(mx[2], mx[6]); mx[3] = fmaxf(mx[3], mx[7]);
            mx[0] = fmaxf(mx[0], mx[2]); mx[1] = fmaxf(mx[1], mx[3]);
            float pmax;
            {
                float2 sw = swap32(fmaxf(mx[0], mx[1]));
                pmax = fmaxf(sw.x, sw.y);
            }

            // defer-max (T13): only rescale when the row max grew by > 8 (log2 domain)
            unsigned long long need = __ballot(pmax > mrun + 8.0f);
            float fc = 1.0f;
            if (need) {
                float nm = fmaxf(mrun, pmax);
                fc = exp2f(mrun - nm);
                mrun = nm;
            }
#pragma unroll
            for (int r = 0; r < 16; ++r) {
                sc0[r] = exp2f(sc0[r] - mrun);
                sc1[r] = exp2f(sc1[r] - mrun);
            }
            // tree sum + cross-half
            float sm[8];
#pragma unroll
            for (int r = 0; r < 8; ++r)
                sm[r] = (sc0[r] + sc0[r + 8]) + (sc1[r] + sc1[r + 8]);
            sm[0] += sm[4]; sm[1] += sm[5]; sm[2] += sm[6]; sm[3] += sm[7];
            sm[0] += sm[2]; sm[1] += sm[3];
            float ps;
            {
                float2 sw = swap32(sm[0] + sm[1]);
                ps = sw.x + sw.y;
            }
            if (need) {
                lsum = lsum * fc + ps;
#pragma unroll
                for (int i = 0; i < 16; ++i) { accO0[i] *= fc; accO1[i] *= fc; }
            } else {
                lsum += ps;
            }

            // pack P -> bf16 B-fragments via cvt_pk + permlane32_swap (no LDS)
            bf16x8 pf[4];
#pragma unroll
            for (int c = 0; c < 4; ++c) {
                const int bb = (c & 1) * 8;
                float s0, s1, s2, s3, s4, s5, s6, s7;
                if (c < 2) {
                    s0 = sc0[bb + 0]; s1 = sc0[bb + 1]; s2 = sc0[bb + 2]; s3 = sc0[bb + 3];
                    s4 = sc0[bb + 4]; s5 = sc0[bb + 5]; s6 = sc0[bb + 6]; s7 = sc0[bb + 7];
                } else {
                    s0 = sc1[bb + 0]; s1 = sc1[bb + 1]; s2 = sc1[bb + 2]; s3 = sc1[bb + 3];
                    s4 = sc1[bb + 4]; s5 = sc1[bb + 5]; s6 = sc1[bb + 6]; s7 = sc1[bb + 7];
                }
                u32 A  = cvtpk(s0, s1);
                u32 A2 = cvtpk(s2, s3);
                u32 Bp = cvtpk(s4, s5);
                u32 B2 = cvtpk(s6, s7);
                u32x2 r02 = __builtin_amdgcn_permlane32_swap(A, Bp, 0, 0);
                u32x2 r13 = __builtin_amdgcn_permlane32_swap(A2, B2, 0, 0);
                union { u32 w[4]; bf16x8 v; } pu;
                pu.w[0] = r02[0]; pu.w[1] = r13[0];
                pu.w[2] = r02[1]; pu.w[3] = r13[1];
                pf[c] = pu.v;
            }

            __builtin_amdgcn_s_setprio(1);
#pragma unroll
            for (int c = 0; c < 4; ++c) {
                int u = ((c << 1) | hi) ^ (ln & 7);
                bf16x8 vf0 = *(const bf16x8*)(sVb + ln * 64 + u * 8);
                bf16x8 vf1 = *(const bf16x8*)(sVb + (32 + ln) * 64 + u * 8);
                accO0 = __builtin_amdgcn_mfma_f32_32x32x16_bf16(vf0, pf[c], accO0, 0, 0, 0);
                accO1 = __builtin_amdgcn_mfma_f32_32x32x16_bf16(vf1, pf[c], accO1, 0, 0, 0);
            }
            __builtin_amdgcn_s_setprio(0);
        }
        asm volatile("s_waitcnt vmcnt(0)" ::: "memory");
        __syncthreads();
        nb ^= 1;
    }

    const float linv = 1.0f / lsum;
    u16* orow = Og + ((size_t)(b * TSEQ + qglob)) * DMODEL + h * HDIM;
#pragma unroll
    for (int a = 0; a < 4; ++a) {
        int d0 = 8 * a + 4 * hi;
        uint2 wo;
        wo.x = cvtpk(accO0[4 * a + 0] * linv, accO0[4 * a + 1] * linv);
        wo.y = cvtpk(accO0[4 * a + 2] * linv, accO0[4 * a + 3] * linv);
        *(uint2*)(orow + d0) = wo;
        wo.x = cvtpk(accO1[4 * a + 0] * linv, accO1[4 * a + 1] * linv);
        wo.y = cvtpk(accO1[4 * a + 2] * linv, accO1[4 * a + 3] * linv);
        *(uint2*)(orow + 32 + d0) = wo;
    }
}

// ---------------- launch ----------------
extern "C" void kernel_launch(void* const* d_in, const int* in_sizes, int n_in,
                              void* d_out, int out_size, void* d_ws, size_t ws_size,
                              hipStream_t stream) {
    const float* x  = (const float*)d_in[0];
    const float* Wq = (const float*)d_in[1];
    const float* bq = (const float*)d_in[2];
    const float* Wk = (const float*)d_in[3];
    const float* bk = (const float*)d_in[4];
    const float* Wv = (const float*)d_in[5];
    const float* bv = (const float*)d_in[6];
    const float* Wo = (const float*)d_in[7];
    const float* bo = (const float*)d_in[8];
    float* out = (float*)d_out;

    u16* ws  = (u16*)d_ws;
    u16* xb  = ws;
    u16* WqT = xb  + (size_t)MTOT * DMODEL;
    u16* WkT = WqT + (size_t)DMODEL * DMODEL;
    u16* WvT = WkT + (size_t)DMODEL * DMODEL;
    u16* WoT = WvT + (size_t)DMODEL * DMODEL;
    u16* Qg  = WoT + (size_t)DMODEL * DMODEL;
    u16* Kg  = Qg  + (size_t)MTOT * DMODEL;
    u16* VTg = Kg  + (size_t)MTOT * DMODEL;
    u16* Og  = VTg + (size_t)MTOT * DMODEL;
    float* biasP = (float*)(Og + (size_t)MTOT * DMODEL);   // 3072 floats

    prep<<<5132, 256, 0, stream>>>(x, Wq, Wk, Wv, Wo, bq, bk, bv,
                                   xb, WqT, WkT, WvT, WoT, biasP);

    // fused QKV: N = 3072 (WqT|WkT|WvT contiguous)
    gemm_bt<0><<<dim3(24, MTOT / 128), 256, 0, stream>>>(xb, WqT, biasP,
                                                         Qg, Kg, VTg, nullptr, DMODEL);

    attn<<<dim3(64, 16), 256, 0, stream>>>(Qg, Kg, VTg, Og);

    gemm_bt<3><<<dim3(8, MTOT / 128), 256, 0, stream>>>(Og, WoT, bo,
                                                        nullptr, nullptr, nullptr, out, DMODEL);
}